// Round 2
// baseline (4043.394 us; speedup 1.0000x reference)
//
#include <hip/hip_runtime.h>
#include <math.h>
#include <stdint.h>

typedef unsigned int u32;
typedef unsigned long long u64;

#define NM   65536
#define HD   1024
#define KS   128
#define SQ   258
#define NH_  16
#define NL   4
#define NBIN 65536
#define CCAP 4096

struct Ctrl { u32 b1, above1, T, candcnt; };

static constexpr size_t A256(size_t x){ return (x + 255) & ~(size_t)255; }

constexpr size_t OFF_KEYS = 0;
constexpr size_t OFF_HIST = A256(OFF_KEYS + (size_t)NM*4);
constexpr size_t OFF_PREF = A256(OFF_HIST + (size_t)NBIN*4);
constexpr size_t OFF_CNT  = A256(OFF_PREF + (size_t)(NBIN+1)*4);
constexpr size_t OFF_LO   = A256(OFF_CNT  + (size_t)NBIN*4);
constexpr size_t OFF_R0   = A256(OFF_LO   + (size_t)NM*4);
constexpr size_t OFF_R1   = A256(OFF_R0   + (size_t)NM*4);
constexpr size_t OFF_R2   = A256(OFF_R1   + (size_t)NM*4);
constexpr size_t OFF_CAND = A256(OFF_R2   + (size_t)NM*4);
constexpr size_t OFF_CTRL = A256(OFF_CAND + (size_t)CCAP*8);
constexpr size_t OFF_IDX  = A256(OFF_CTRL + 256);
constexpr size_t OFF_XN   = A256(OFF_IDX  + (size_t)KS*4);
constexpr size_t OFF_SIM  = A256(OFF_XN   + (size_t)HD*4);
constexpr size_t OFF_SEL  = A256(OFF_SIM  + (size_t)NM*4);
constexpr size_t OFF_HM   = A256(OFF_SEL  + (size_t)KS*HD*4);
constexpr size_t OFF_HT   = A256(OFF_HM   + (size_t)KS*HD*4);
constexpr size_t OFF_AVM  = A256(OFF_HT   + (size_t)KS*HD*4);
constexpr size_t OFF_AVT  = A256(OFF_AVM  + (size_t)KS*HD*4);
constexpr size_t OFF_REW  = A256(OFF_AVT  + (size_t)KS*HD*4);
constexpr size_t OFF_VECS = A256(OFF_REW  + (size_t)KS*4);
constexpr size_t OFF_LNB  = A256(OFF_VECS + (size_t)SQ*HD*4);
constexpr size_t OFF_QKV  = A256(OFF_LNB  + (size_t)SQ*HD*4);
constexpr size_t OFF_ATT  = A256(OFF_QKV  + (size_t)SQ*3*HD*4);
constexpr size_t OFF_FFH  = A256(OFF_ATT  + (size_t)SQ*HD*4);
constexpr size_t OFF_VHIN = A256(OFF_FFH  + (size_t)SQ*4*HD*4);
constexpr size_t OFF_VHH  = A256(OFF_VHIN + (size_t)129*HD*4);
constexpr size_t OFF_VP   = A256(OFF_VHH  + (size_t)129*4096*4);

// output layout (floats)
constexpr int OUT_NEXT = 257*HD;          // 263168
constexpr int OUT_VP   = OUT_NEXT + KS*HD; // 394240
constexpr int OUT_LOSS = OUT_VP + 1;
constexpr int OUT_REWO = OUT_LOSS + KS;

__device__ __forceinline__ float gelu_f(float v){
  return 0.5f*v*(1.0f + erff(v*0.70710678118654752440f));
}

// ----------------- scoring -----------------
__global__ void k_xnorm(const float* __restrict__ x, float* __restrict__ xn){
  __shared__ float red[256];
  int t = threadIdx.x;
  float s = 0.f;
  for(int i=t;i<HD;i+=256){ float v=x[i]; s += v*v; }
  red[t]=s; __syncthreads();
  for(int o=128;o>0;o>>=1){ if(t<o) red[t]+=red[t+o]; __syncthreads(); }
  float nrm = fmaxf(sqrtf(red[0]), 1e-8f);
  for(int i=t;i<HD;i+=256) xn[i] = x[i]/nrm;
}

__global__ void k_sim(const float* __restrict__ mv, const float* __restrict__ xn, float* __restrict__ sim){
  __shared__ float r1[256], r2[256];
  int row = blockIdx.x, t = threadIdx.x;
  const float* p = mv + (size_t)row*HD;
  float d=0.f, ss=0.f;
  for(int i=t;i<HD;i+=256){ float v=p[i]; d += v*xn[i]; ss += v*v; }
  r1[t]=d; r2[t]=ss; __syncthreads();
  for(int o=128;o>0;o>>=1){ if(t<o){ r1[t]+=r1[t+o]; r2[t]+=r2[t+o]; } __syncthreads(); }
  if(t==0) sim[row] = r1[0] / fmaxf(sqrtf(r2[0]), 1e-8f);
}

// ----------------- tie-aware ranking -----------------
__global__ void k_keyhist(const float* __restrict__ v, u32* __restrict__ keys, u32* __restrict__ hist){
  int i = blockIdx.x*256 + threadIdx.x;
  if(i >= NM) return;
  u32 b = __float_as_uint(v[i]);
  u32 k = (b >> 31) ? ~b : (b | 0x80000000u);
  keys[i] = k;
  atomicAdd(&hist[k >> 16], 1u);
}

__global__ __launch_bounds__(1024) void k_scan(const u32* __restrict__ hist, u32* __restrict__ prefix){
  __shared__ u32 part[1024];
  int t = threadIdx.x;
  u32 base = t*64, s = 0;
  for(int j=0;j<64;++j) s += hist[base+j];
  part[t] = s; __syncthreads();
  for(int off=1;off<1024;off<<=1){
    u32 v = (t >= off) ? part[t-off] : 0u;
    __syncthreads();
    part[t] += v;
    __syncthreads();
  }
  u32 run = part[t] - s;
  for(int j=0;j<64;++j){ prefix[base+j] = run; run += hist[base+j]; }
  if(t == 1023) prefix[NBIN] = run;
}

__global__ void k_scatter(const u32* __restrict__ keys, const u32* __restrict__ prefix,
                          u32* __restrict__ cnt, u32* __restrict__ lo){
  int i = blockIdx.x*256 + threadIdx.x;
  if(i >= NM) return;
  u32 k = keys[i];
  u32 b = k >> 16;
  u32 pos = prefix[b] + atomicAdd(&cnt[b], 1u);
  lo[pos] = k & 0xFFFFu;
}

__global__ void k_rank(const u32* __restrict__ keys, const u32* __restrict__ prefix,
                       const u32* __restrict__ lo, float* __restrict__ rank){
  int i = blockIdx.x*256 + threadIdx.x;
  if(i >= NM) return;
  u32 k = keys[i];
  u32 b = k >> 16, my = k & 0xFFFFu;
  u32 s = prefix[b], e = prefix[b+1];
  u32 nl = 0, ne = 0;
  for(u32 j=s;j<e;++j){ u32 u = lo[j]; nl += (u < my); ne += (u == my); }
  u32 left = s + nl, right = left + ne;
  rank[i] = (float)(left + right - 1) * (1.0f/131072.0f);  // exact: (l+r-1)/2/65536
}

__global__ void k_score(const float* __restrict__ r0, const float* __restrict__ r1,
                        const float* __restrict__ r2, u32* __restrict__ keys, u32* __restrict__ hist){
  int i = blockIdx.x*256 + threadIdx.x;
  if(i >= NM) return;
  float a = r0[i], b = r1[i], c = r2[i];
  float s = __fadd_rn(__fadd_rn(__fmul_rn(a,a), __fmul_rn(b,b)), __fmul_rn(c,c));
  u32 k = __float_as_uint(s);   // s >= 0 -> bits monotone
  keys[i] = k;
  atomicAdd(&hist[k >> 16], 1u);
}

// ----------------- top-k select -----------------
__global__ __launch_bounds__(1024) void k_sel1(const u32* __restrict__ hist, Ctrl* ctrl){
  __shared__ u32 part[1024];
  int t = threadIdx.x;
  u32 base = t*64, s = 0;
  for(int j=0;j<64;++j) s += hist[base+j];
  part[t] = s; __syncthreads();
  for(int off=1;off<1024;off<<=1){
    u32 v = (t+off < 1024) ? part[t+off] : 0u;
    __syncthreads();
    part[t] += v;
    __syncthreads();
  }
  u32 above = part[t] - s;  // count strictly above this chunk
  if(above < (u32)KS && above + s >= (u32)KS){
    u32 cum = above;
    for(int j=63;j>=0;--j){
      u32 c = hist[base+j];
      if(cum + c >= (u32)KS){ ctrl->b1 = base+j; ctrl->above1 = cum; break; }
      cum += c;
    }
  }
}

__global__ void k_histlo(const u32* __restrict__ keys, const Ctrl* ctrl, u32* __restrict__ h){
  int i = blockIdx.x*256 + threadIdx.x;
  if(i >= NM) return;
  u32 k = keys[i];
  if((k >> 16) == ctrl->b1) atomicAdd(&h[k & 0xFFFFu], 1u);
}

__global__ __launch_bounds__(1024) void k_sel2(const u32* __restrict__ hist, Ctrl* ctrl){
  __shared__ u32 part[1024];
  int t = threadIdx.x;
  u32 target = (u32)KS - ctrl->above1;
  u32 base = t*64, s = 0;
  for(int j=0;j<64;++j) s += hist[base+j];
  part[t] = s; __syncthreads();
  for(int off=1;off<1024;off<<=1){
    u32 v = (t+off < 1024) ? part[t+off] : 0u;
    __syncthreads();
    part[t] += v;
    __syncthreads();
  }
  u32 above = part[t] - s;
  if(above < target && above + s >= target){
    u32 cum = above;
    for(int j=63;j>=0;--j){
      u32 c = hist[base+j];
      if(cum + c >= target){
        ctrl->T = (ctrl->b1 << 16) | (base+j);
        ctrl->candcnt = 0;
        break;
      }
      cum += c;
    }
  }
}

__global__ void k_collect(const u32* __restrict__ keys, Ctrl* ctrl, u64* __restrict__ cand){
  int i = blockIdx.x*256 + threadIdx.x;
  if(i >= NM) return;
  u32 k = keys[i];
  if(k >= ctrl->T){
    u32 p = atomicAdd(&ctrl->candcnt, 1u);
    if(p < (u32)CCAP) cand[p] = ((u64)(~k) << 32) | (u32)i;
  }
}

__global__ __launch_bounds__(1024) void k_sortsel(const u64* __restrict__ cand, const Ctrl* ctrl, int* __restrict__ idx){
  __shared__ u64 sm[CCAP];
  int t = threadIdx.x;
  u32 n = ctrl->candcnt; if(n > (u32)CCAP) n = CCAP;
  for(int i=t;i<CCAP;i+=1024) sm[i] = (i < (int)n) ? cand[i] : 0xFFFFFFFFFFFFFFFFull;
  __syncthreads();
  for(int k=2;k<=CCAP;k<<=1){
    for(int j=k>>1;j>0;j>>=1){
      for(int i=t;i<CCAP;i+=1024){
        int ixj = i ^ j;
        if(ixj > i){
          bool up = ((i & k) == 0);
          u64 a = sm[i], b = sm[ixj];
          if((a > b) == up){ sm[i] = b; sm[ixj] = a; }
        }
      }
      __syncthreads();
    }
  }
  if(t < KS) idx[t] = (int)(sm[t] & 0xFFFFFFFFu);
}

// ----------------- gathers + action MLP hidden -----------------
__global__ void k_gather(const int* __restrict__ idx,
                         const float* __restrict__ mv, const float* __restrict__ mnv,
                         const float* __restrict__ mrew,
                         const int* __restrict__ aim, const int* __restrict__ ait,
                         const float* __restrict__ amw1, const float* __restrict__ amb1,
                         const float* __restrict__ atw1, const float* __restrict__ atb1,
                         float* __restrict__ sel, float* __restrict__ outnext,
                         float* __restrict__ hm, float* __restrict__ ht,
                         float* __restrict__ rew, float* __restrict__ outrew){
  int k = blockIdx.x;
  int row = idx[k];
  const float* a = mv  + (size_t)row*HD;
  const float* b = mnv + (size_t)row*HD;
  for(int c=threadIdx.x;c<HD;c+=256){
    sel[(size_t)k*HD+c] = a[c];
    outnext[(size_t)k*HD+c] = b[c];
  }
  int am = aim[row], at = ait[row];
  for(int j=threadIdx.x;j<HD;j+=256){
    hm[(size_t)k*HD+j] = gelu_f(amw1[(size_t)j*9 + am] + amb1[j]);
    ht[(size_t)k*HD+j] = gelu_f(atw1[(size_t)j*4 + at] + atb1[j]);
  }
  if(threadIdx.x == 0){ float r = mrew[row]; rew[k] = r; outrew[k] = r; }
}

// ----------------- generic fp32 GEMM: C = act(A @ B^T + bias) (+res) -----------------
template<int ACT, bool BIAS, bool RES>
__global__ __launch_bounds__(256) void gemm_nt(const float* __restrict__ A, const float* __restrict__ B,
        const float* __restrict__ bias, const float* __restrict__ res, float* __restrict__ C,
        int M, int Nd, int Kd){
  __shared__ float As[16][68];
  __shared__ float Bs[16][68];
  int bm = blockIdx.x*64, bn = blockIdx.y*64;
  int tid = threadIdx.x;
  int lk = tid & 15, lr = tid >> 4;
  int tx = tid & 15, ty = tid >> 4;
  float acc[4][4] = {};
  for(int k0=0;k0<Kd;k0+=16){
    #pragma unroll
    for(int r=0;r<4;++r){
      int m = bm + lr + r*16;
      As[lk][lr + r*16] = (m < M) ? A[(size_t)m*Kd + k0 + lk] : 0.0f;
      Bs[lk][lr + r*16] = B[(size_t)(bn + lr + r*16)*Kd + k0 + lk];
    }
    __syncthreads();
    #pragma unroll
    for(int kk=0;kk<16;++kk){
      float4 av = *(const float4*)&As[kk][ty*4];
      float4 bv = *(const float4*)&Bs[kk][tx*4];
      acc[0][0] += av.x*bv.x; acc[0][1] += av.x*bv.y; acc[0][2] += av.x*bv.z; acc[0][3] += av.x*bv.w;
      acc[1][0] += av.y*bv.x; acc[1][1] += av.y*bv.y; acc[1][2] += av.y*bv.z; acc[1][3] += av.y*bv.w;
      acc[2][0] += av.z*bv.x; acc[2][1] += av.z*bv.y; acc[2][2] += av.z*bv.z; acc[2][3] += av.z*bv.w;
      acc[3][0] += av.w*bv.x; acc[3][1] += av.w*bv.y; acc[3][2] += av.w*bv.z; acc[3][3] += av.w*bv.w;
    }
    __syncthreads();
  }
  #pragma unroll
  for(int i=0;i<4;++i){
    int m = bm + ty*4 + i;
    if(m >= M) continue;
    #pragma unroll
    for(int j=0;j<4;++j){
      int n = bn + tx*4 + j;
      float v = acc[i][j];
      if(BIAS) v += bias[n];
      if(ACT == 1) v = gelu_f(v);
      if(RES) v += res[(size_t)m*Nd + n];
      C[(size_t)m*Nd + n] = v;
    }
  }
}

// ----------------- layernorm -----------------
__global__ void k_ln(const float* __restrict__ in, const float* __restrict__ w, const float* __restrict__ b,
                     float* __restrict__ outp){
  __shared__ float red[256];
  int row = blockIdx.x, t = threadIdx.x;
  const float* xr = in + (size_t)row*HD;
  float s = 0.f;
  for(int i=t;i<HD;i+=256) s += xr[i];
  red[t]=s; __syncthreads();
  for(int o=128;o>0;o>>=1){ if(t<o) red[t]+=red[t+o]; __syncthreads(); }
  float m = red[0] * (1.0f/HD);
  __syncthreads();
  float ss = 0.f;
  for(int i=t;i<HD;i+=256){ float d = xr[i]-m; ss += d*d; }
  red[t]=ss; __syncthreads();
  for(int o=128;o>0;o>>=1){ if(t<o) red[t]+=red[t+o]; __syncthreads(); }
  float var = red[0] * (1.0f/HD);
  float denom = sqrtf(var + 1e-5f);
  for(int i=t;i<HD;i+=256) outp[(size_t)row*HD+i] = (xr[i]-m)/denom * w[i] + b[i];
}

// ----------------- attention -----------------
__global__ void k_attn(const float* __restrict__ qkv, float* __restrict__ outp){
  __shared__ float qv[64];
  __shared__ float p[SQ];
  __shared__ float red[256];
  int q = blockIdx.x, h = blockIdx.y, t = threadIdx.x;
  if(t < 64) qv[t] = qkv[(size_t)q*3072 + h*64 + t];
  __syncthreads();
  int nk = q + 1;
  float lmax = -1e30f;
  for(int j=t;j<nk;j+=256){
    const float* kr = qkv + (size_t)j*3072 + 1024 + h*64;
    float d = 0.f;
    for(int c=0;c<64;++c) d += qv[c]*kr[c];
    d *= 0.125f;
    p[j] = d;
    lmax = fmaxf(lmax, d);
  }
  red[t] = lmax; __syncthreads();
  for(int o=128;o>0;o>>=1){ if(t<o) red[t] = fmaxf(red[t], red[t+o]); __syncthreads(); }
  float m = red[0];
  __syncthreads();
  float lsum = 0.f;
  for(int j=t;j<nk;j+=256){ float e = expf(p[j]-m); p[j] = e; lsum += e; }
  red[t] = lsum; __syncthreads();
  for(int o=128;o>0;o>>=1){ if(t<o) red[t] += red[t+o]; __syncthreads(); }
  float inv = 1.0f/red[0];
  __syncthreads();
  int d = t & 63, g = t >> 6;
  float acc = 0.f;
  for(int j=g;j<nk;j+=4) acc += p[j]*qkv[(size_t)j*3072 + 2048 + h*64 + d];
  red[t] = acc; __syncthreads();
  if(g == 0){
    float o4 = red[d] + red[64+d] + red[128+d] + red[192+d];
    outp[(size_t)q*HD + h*64 + d] = o4*inv;
  }
}

// ----------------- assembly / heads / outputs -----------------
__global__ void k_assemble(const float* __restrict__ start, const float* __restrict__ x,
                           const float* __restrict__ sel, const float* __restrict__ avm,
                           const float* __restrict__ avt, const float* __restrict__ pos,
                           float* __restrict__ vecs){
  int row = blockIdx.x;
  for(int j=threadIdx.x;j<HD;j+=256){
    float v;
    if(row == 0) v = start[j];
    else if(row == SQ-1) v = x[j];
    else if(row & 1) v = sel[(size_t)((row-1)>>1)*HD + j];
    else { int tt = (row-2)>>1; v = 0.5f*(avm[(size_t)tt*HD+j] + avt[(size_t)tt*HD+j]); }
    vecs[(size_t)row*HD + j] = v + pos[(size_t)row*HD + j];
  }
}

__global__ void k_vhin(const float* __restrict__ vecs, float* __restrict__ vhin){
  int r = blockIdx.x;
  const float* src = vecs + (size_t)(2*r+1)*HD;
  for(int j=threadIdx.x;j<HD;j+=256) vhin[(size_t)r*HD+j] = src[j];
}

__global__ void k_vp(const float* __restrict__ vhh, const float* __restrict__ w2,
                     const float* __restrict__ b2, float* __restrict__ vp){
  __shared__ float red[256];
  int r = blockIdx.x, t = threadIdx.x;
  float s = 0.f;
  for(int i=t;i<4096;i+=256) s += vhh[(size_t)r*4096+i]*w2[i];
  red[t]=s; __syncthreads();
  for(int o=128;o>0;o>>=1){ if(t<o) red[t]+=red[t+o]; __syncthreads(); }
  if(t == 0) vp[r] = red[0] + b2[0];
}

__global__ void k_outvecs(const float* __restrict__ vecs, float* __restrict__ outp){
  int i = blockIdx.x*256 + threadIdx.x;
  if(i < 257*HD) outp[i] = vecs[HD + i];
}

__global__ void k_outsmall(const float* __restrict__ vp, const float* __restrict__ rew, float* __restrict__ outp){
  int t = threadIdx.x;
  if(t == 0) outp[OUT_VP] = vp[KS];
  if(t < KS){
    float d = vp[t] - rew[t];
    outp[OUT_LOSS + t] = d*d;
    outp[OUT_REWO + t] = rew[t];
  }
}

extern "C" void kernel_launch(void* const* d_in, const int* in_sizes, int n_in,
                              void* d_out, int out_size, void* d_ws, size_t ws_size,
                              hipStream_t stream){
  const float* x     = (const float*)d_in[0];
  const float* mv    = (const float*)d_in[1];
  const float* mnv   = (const float*)d_in[2];
  const float* surp  = (const float*)d_in[3];
  const float* mrew  = (const float*)d_in[4];
  const float* noise = (const float*)d_in[5];
  const int*   aim   = (const int*)d_in[6];
  const int*   ait   = (const int*)d_in[7];
  const float* start = (const float*)d_in[8];
  const float* pos   = (const float*)d_in[9];
  const float* inW = (const float*)d_in[10]; const float* inB = (const float*)d_in[11];
  const float* oW  = (const float*)d_in[12]; const float* oB  = (const float*)d_in[13];
  const float* l1w = (const float*)d_in[14]; const float* l1b = (const float*)d_in[15];
  const float* l2w = (const float*)d_in[16]; const float* l2b = (const float*)d_in[17];
  const float* f1w = (const float*)d_in[18]; const float* f1b = (const float*)d_in[19];
  const float* f2w = (const float*)d_in[20]; const float* f2b = (const float*)d_in[21];
  const float* amw1= (const float*)d_in[22]; const float* amb1= (const float*)d_in[23];
  const float* amw2= (const float*)d_in[24]; const float* amb2= (const float*)d_in[25];
  const float* atw1= (const float*)d_in[26]; const float* atb1= (const float*)d_in[27];
  const float* atw2= (const float*)d_in[28]; const float* atb2= (const float*)d_in[29];
  const float* vw1 = (const float*)d_in[30]; const float* vb1 = (const float*)d_in[31];
  const float* vw2 = (const float*)d_in[32]; const float* vb2 = (const float*)d_in[33];

  float* out = (float*)d_out;
  char* ws = (char*)d_ws;
  u32*  keys = (u32*)(ws+OFF_KEYS);
  u32*  hist = (u32*)(ws+OFF_HIST);
  u32*  pref = (u32*)(ws+OFF_PREF);
  u32*  cnt  = (u32*)(ws+OFF_CNT);
  u32*  lo   = (u32*)(ws+OFF_LO);
  float* r0  = (float*)(ws+OFF_R0);
  float* r1  = (float*)(ws+OFF_R1);
  float* r2  = (float*)(ws+OFF_R2);
  u64*  cand = (u64*)(ws+OFF_CAND);
  Ctrl* ctrl = (Ctrl*)(ws+OFF_CTRL);
  int*  idxb = (int*)(ws+OFF_IDX);
  float* xn  = (float*)(ws+OFF_XN);
  float* simv= (float*)(ws+OFF_SIM);
  float* sel = (float*)(ws+OFF_SEL);
  float* hm  = (float*)(ws+OFF_HM);
  float* ht  = (float*)(ws+OFF_HT);
  float* avm = (float*)(ws+OFF_AVM);
  float* avt = (float*)(ws+OFF_AVT);
  float* rew = (float*)(ws+OFF_REW);
  float* vecs= (float*)(ws+OFF_VECS);
  float* lnb = (float*)(ws+OFF_LNB);
  float* qkvb= (float*)(ws+OFF_QKV);
  float* attn= (float*)(ws+OFF_ATT);
  float* ffh = (float*)(ws+OFF_FFH);
  float* vhin= (float*)(ws+OFF_VHIN);
  float* vhh = (float*)(ws+OFF_VHH);
  float* vp  = (float*)(ws+OFF_VP);

  dim3 b256(256);
  int gN = NM/256;

  // ---- scoring ----
  hipLaunchKernelGGL(k_xnorm, dim3(1), b256, 0, stream, x, xn);
  hipLaunchKernelGGL(k_sim, dim3(NM), b256, 0, stream, mv, xn, simv);

  const float* rank_src[3] = { surp, simv, noise };
  float* rank_dst[3] = { r0, r1, r2 };
  for(int a=0;a<3;++a){
    (void)hipMemsetAsync(hist, 0, (size_t)NBIN*4, stream);
    (void)hipMemsetAsync(cnt,  0, (size_t)NBIN*4, stream);
    hipLaunchKernelGGL(k_keyhist, dim3(gN), b256, 0, stream, rank_src[a], keys, hist);
    hipLaunchKernelGGL(k_scan, dim3(1), dim3(1024), 0, stream, hist, pref);
    hipLaunchKernelGGL(k_scatter, dim3(gN), b256, 0, stream, keys, pref, cnt, lo);
    hipLaunchKernelGGL(k_rank, dim3(gN), b256, 0, stream, keys, pref, lo, rank_dst[a]);
  }

  (void)hipMemsetAsync(hist, 0, (size_t)NBIN*4, stream);
  hipLaunchKernelGGL(k_score, dim3(gN), b256, 0, stream, r0, r1, r2, keys, hist);
  hipLaunchKernelGGL(k_sel1, dim3(1), dim3(1024), 0, stream, hist, ctrl);
  (void)hipMemsetAsync(cnt, 0, (size_t)NBIN*4, stream);
  hipLaunchKernelGGL(k_histlo, dim3(gN), b256, 0, stream, keys, ctrl, cnt);
  hipLaunchKernelGGL(k_sel2, dim3(1), dim3(1024), 0, stream, cnt, ctrl);
  hipLaunchKernelGGL(k_collect, dim3(gN), b256, 0, stream, keys, ctrl, cand);
  hipLaunchKernelGGL(k_sortsel, dim3(1), dim3(1024), 0, stream, cand, ctrl, idxb);

  // ---- gathers + action MLP ----
  hipLaunchKernelGGL(k_gather, dim3(KS), b256, 0, stream, idxb, mv, mnv, mrew, aim, ait,
                     amw1, amb1, atw1, atb1, sel, out + OUT_NEXT, hm, ht, rew, out + OUT_REWO);
  hipLaunchKernelGGL((gemm_nt<0,true,false>), dim3(2,16), b256, 0, stream, hm, amw2, amb2, (const float*)nullptr, avm, KS, HD, HD);
  hipLaunchKernelGGL((gemm_nt<0,true,false>), dim3(2,16), b256, 0, stream, ht, atw2, atb2, (const float*)nullptr, avt, KS, HD, HD);
  hipLaunchKernelGGL(k_assemble, dim3(SQ), b256, 0, stream, start, x, sel, avm, avt, pos, vecs);

  // ---- transformer ----
  for(int l=0;l<NL;++l){
    hipLaunchKernelGGL(k_ln, dim3(SQ), b256, 0, stream, vecs, l1w + (size_t)l*HD, l1b + (size_t)l*HD, lnb);
    hipLaunchKernelGGL((gemm_nt<0,true,false>), dim3(5,48), b256, 0, stream,
                       lnb, inW + (size_t)l*3*HD*HD, inB + (size_t)l*3*HD, (const float*)nullptr, qkvb, SQ, 3*HD, HD);
    hipLaunchKernelGGL(k_attn, dim3(SQ, NH_), b256, 0, stream, qkvb, attn);
    hipLaunchKernelGGL((gemm_nt<0,true,true>), dim3(5,16), b256, 0, stream,
                       attn, oW + (size_t)l*HD*HD, oB + (size_t)l*HD, vecs, vecs, SQ, HD, HD);
    hipLaunchKernelGGL(k_ln, dim3(SQ), b256, 0, stream, vecs, l2w + (size_t)l*HD, l2b + (size_t)l*HD, lnb);
    hipLaunchKernelGGL((gemm_nt<1,true,false>), dim3(5,64), b256, 0, stream,
                       lnb, f1w + (size_t)l*4*HD*HD, f1b + (size_t)l*4*HD, (const float*)nullptr, ffh, SQ, 4*HD, HD);
    hipLaunchKernelGGL((gemm_nt<0,true,true>), dim3(5,16), b256, 0, stream,
                       ffh, f2w + (size_t)l*HD*4*HD, f2b + (size_t)l*HD, vecs, vecs, SQ, HD, 4*HD);
  }

  // ---- value head + outputs ----
  hipLaunchKernelGGL(k_vhin, dim3(KS+1), b256, 0, stream, vecs, vhin);
  hipLaunchKernelGGL((gemm_nt<1,true,false>), dim3(3,64), b256, 0, stream,
                     vhin, vw1, vb1, (const float*)nullptr, vhh, KS+1, 4*HD, HD);
  hipLaunchKernelGGL(k_vp, dim3(KS+1), b256, 0, stream, vhh, vw2, vb2, vp);
  hipLaunchKernelGGL(k_outvecs, dim3(257*HD/256), b256, 0, stream, vecs, out);
  hipLaunchKernelGGL(k_outsmall, dim3(1), b256, 0, stream, vp, rew, out);
}

// Round 3
// 1189.125 us; speedup vs baseline: 3.4003x; 3.4003x over previous
//
#include <hip/hip_runtime.h>
#include <math.h>
#include <stdint.h>

typedef unsigned int u32;
typedef unsigned long long u64;

#define NM   65536
#define HD   1024
#define KS   128
#define SQ   258
#define NH_  16
#define NL   4
#define NBIN 65536
#define CCAP 4096

using bf16x8 = __attribute__((ext_vector_type(8))) short;
using f32x4v = __attribute__((ext_vector_type(4))) float;

struct Ctrl { u32 b1, above1, T, candcnt; };

static constexpr size_t A256(size_t x){ return (x + 255) & ~(size_t)255; }

constexpr size_t OFF_KEYS = 0;
constexpr size_t OFF_HIST = A256(OFF_KEYS + (size_t)NM*4);
constexpr size_t OFF_PREF = A256(OFF_HIST + (size_t)NBIN*4);
constexpr size_t OFF_CNT  = A256(OFF_PREF + (size_t)(NBIN+1)*4);
constexpr size_t OFF_LO   = A256(OFF_CNT  + (size_t)NBIN*4);
constexpr size_t OFF_R0   = A256(OFF_LO   + (size_t)NM*4);
constexpr size_t OFF_R1   = A256(OFF_R0   + (size_t)NM*4);
constexpr size_t OFF_R2   = A256(OFF_R1   + (size_t)NM*4);
constexpr size_t OFF_CAND = A256(OFF_R2   + (size_t)NM*4);
constexpr size_t OFF_CTRL = A256(OFF_CAND + (size_t)CCAP*8);
constexpr size_t OFF_IDX  = A256(OFF_CTRL + 256);
constexpr size_t OFF_XN   = A256(OFF_IDX  + (size_t)KS*4);
constexpr size_t OFF_SIM  = A256(OFF_XN   + (size_t)HD*4);
constexpr size_t OFF_SEL  = A256(OFF_SIM  + (size_t)NM*4);
constexpr size_t OFF_HM   = A256(OFF_SEL  + (size_t)KS*HD*4);
constexpr size_t OFF_HT   = A256(OFF_HM   + (size_t)KS*HD*4);
constexpr size_t OFF_AVM  = A256(OFF_HT   + (size_t)KS*HD*4);
constexpr size_t OFF_AVT  = A256(OFF_AVM  + (size_t)KS*HD*4);
constexpr size_t OFF_REW  = A256(OFF_AVT  + (size_t)KS*HD*4);
constexpr size_t OFF_VECS = A256(OFF_REW  + (size_t)KS*4);
constexpr size_t OFF_LNB  = A256(OFF_VECS + (size_t)SQ*HD*4);
constexpr size_t OFF_QKV  = A256(OFF_LNB  + (size_t)SQ*HD*4);
constexpr size_t OFF_ATT  = A256(OFF_QKV  + (size_t)SQ*3*HD*4);
constexpr size_t OFF_FFH  = A256(OFF_ATT  + (size_t)SQ*HD*4);
constexpr size_t OFF_VHIN = A256(OFF_FFH  + (size_t)SQ*4*HD*4);
constexpr size_t OFF_VHH  = A256(OFF_VHIN + (size_t)129*HD*4);
constexpr size_t OFF_VP   = A256(OFF_VHH  + (size_t)129*4096*4);
constexpr size_t OFF_PART = A256(OFF_VP   + 256);   // max S*M*N*4 = 8*258*1024*4 ~ 8.5 MB

// output layout (floats)
constexpr int OUT_NEXT = 257*HD;
constexpr int OUT_VP   = OUT_NEXT + KS*HD;
constexpr int OUT_LOSS = OUT_VP + 1;
constexpr int OUT_REWO = OUT_LOSS + KS;

__device__ __forceinline__ float gelu_f(float v){
  return 0.5f*v*(1.0f + erff(v*0.70710678118654752440f));
}

__device__ __forceinline__ short f2bf(float f){
  u32 b = __float_as_uint(f);
  return (short)((b + 0x7FFFu + ((b >> 16) & 1u)) >> 16);
}

// ----------------- scoring -----------------
__global__ void k_xnorm(const float* __restrict__ x, float* __restrict__ xn){
  __shared__ float red[256];
  int t = threadIdx.x;
  float s = 0.f;
  for(int i=t;i<HD;i+=256){ float v=x[i]; s += v*v; }
  red[t]=s; __syncthreads();
  for(int o=128;o>0;o>>=1){ if(t<o) red[t]+=red[t+o]; __syncthreads(); }
  float nrm = fmaxf(sqrtf(red[0]), 1e-8f);
  for(int i=t;i<HD;i+=256) xn[i] = x[i]/nrm;
}

// one wave per row, float4 loads
__global__ __launch_bounds__(256) void k_sim2(const float* __restrict__ mv, const float* __restrict__ xn, float* __restrict__ sim){
  __shared__ float xs[HD];
  int t = threadIdx.x;
  for(int i=t;i<HD;i+=256) xs[i]=xn[i];
  __syncthreads();
  int lane = t & 63, w = t >> 6;
  int row = blockIdx.x*4 + w;
  const float4* p = (const float4*)(mv + (size_t)row*HD);
  const float4* q = (const float4*)xs;
  float d=0.f, ss=0.f;
  #pragma unroll
  for(int r=0;r<4;++r){
    float4 v = p[lane + 64*r]; float4 u = q[lane + 64*r];
    d  += v.x*u.x + v.y*u.y + v.z*u.z + v.w*u.w;
    ss += v.x*v.x + v.y*v.y + v.z*v.z + v.w*v.w;
  }
  for(int off=32;off>0;off>>=1){ d += __shfl_xor(d,off,64); ss += __shfl_xor(ss,off,64); }
  if(lane==0) sim[row] = d / fmaxf(sqrtf(ss),1e-8f);
}

// ----------------- tie-aware ranking -----------------
__global__ void k_keyhist(const float* __restrict__ v, u32* __restrict__ keys, u32* __restrict__ hist){
  int i = blockIdx.x*256 + threadIdx.x;
  if(i >= NM) return;
  u32 b = __float_as_uint(v[i]);
  u32 k = (b >> 31) ? ~b : (b | 0x80000000u);
  keys[i] = k;
  atomicAdd(&hist[k >> 16], 1u);
}

__global__ __launch_bounds__(1024) void k_scan(const u32* __restrict__ hist, u32* __restrict__ prefix){
  __shared__ u32 part[1024];
  int t = threadIdx.x;
  u32 base = t*64, s = 0;
  for(int j=0;j<64;++j) s += hist[base+j];
  part[t] = s; __syncthreads();
  for(int off=1;off<1024;off<<=1){
    u32 v = (t >= off) ? part[t-off] : 0u;
    __syncthreads();
    part[t] += v;
    __syncthreads();
  }
  u32 run = part[t] - s;
  for(int j=0;j<64;++j){ prefix[base+j] = run; run += hist[base+j]; }
  if(t == 1023) prefix[NBIN] = run;
}

__global__ void k_scatter(const u32* __restrict__ keys, const u32* __restrict__ prefix,
                          u32* __restrict__ cnt, u32* __restrict__ lo){
  int i = blockIdx.x*256 + threadIdx.x;
  if(i >= NM) return;
  u32 k = keys[i];
  u32 b = k >> 16;
  u32 pos = prefix[b] + atomicAdd(&cnt[b], 1u);
  lo[pos] = k & 0xFFFFu;
}

__global__ void k_rank(const u32* __restrict__ keys, const u32* __restrict__ prefix,
                       const u32* __restrict__ lo, float* __restrict__ rank){
  int i = blockIdx.x*256 + threadIdx.x;
  if(i >= NM) return;
  u32 k = keys[i];
  u32 b = k >> 16, my = k & 0xFFFFu;
  u32 s = prefix[b], e = prefix[b+1];
  u32 nl = 0, ne = 0;
  for(u32 j=s;j<e;++j){ u32 u = lo[j]; nl += (u < my); ne += (u == my); }
  u32 left = s + nl, right = left + ne;
  rank[i] = (float)(left + right - 1) * (1.0f/131072.0f);
}

__global__ void k_score(const float* __restrict__ r0, const float* __restrict__ r1,
                        const float* __restrict__ r2, u32* __restrict__ keys, u32* __restrict__ hist){
  int i = blockIdx.x*256 + threadIdx.x;
  if(i >= NM) return;
  float a = r0[i], b = r1[i], c = r2[i];
  float s = __fadd_rn(__fadd_rn(__fmul_rn(a,a), __fmul_rn(b,b)), __fmul_rn(c,c));
  u32 k = __float_as_uint(s);
  keys[i] = k;
  atomicAdd(&hist[k >> 16], 1u);
}

// ----------------- top-k select -----------------
__global__ __launch_bounds__(1024) void k_sel1(const u32* __restrict__ hist, Ctrl* ctrl){
  __shared__ u32 part[1024];
  int t = threadIdx.x;
  u32 base = t*64, s = 0;
  for(int j=0;j<64;++j) s += hist[base+j];
  part[t] = s; __syncthreads();
  for(int off=1;off<1024;off<<=1){
    u32 v = (t+off < 1024) ? part[t+off] : 0u;
    __syncthreads();
    part[t] += v;
    __syncthreads();
  }
  u32 above = part[t] - s;
  if(above < (u32)KS && above + s >= (u32)KS){
    u32 cum = above;
    for(int j=63;j>=0;--j){
      u32 c = hist[base+j];
      if(cum + c >= (u32)KS){ ctrl->b1 = base+j; ctrl->above1 = cum; break; }
      cum += c;
    }
  }
}

__global__ void k_histlo(const u32* __restrict__ keys, const Ctrl* ctrl, u32* __restrict__ h){
  int i = blockIdx.x*256 + threadIdx.x;
  if(i >= NM) return;
  u32 k = keys[i];
  if((k >> 16) == ctrl->b1) atomicAdd(&h[k & 0xFFFFu], 1u);
}

__global__ __launch_bounds__(1024) void k_sel2(const u32* __restrict__ hist, Ctrl* ctrl){
  __shared__ u32 part[1024];
  int t = threadIdx.x;
  u32 target = (u32)KS - ctrl->above1;
  u32 base = t*64, s = 0;
  for(int j=0;j<64;++j) s += hist[base+j];
  part[t] = s; __syncthreads();
  for(int off=1;off<1024;off<<=1){
    u32 v = (t+off < 1024) ? part[t+off] : 0u;
    __syncthreads();
    part[t] += v;
    __syncthreads();
  }
  u32 above = part[t] - s;
  if(above < target && above + s >= target){
    u32 cum = above;
    for(int j=63;j>=0;--j){
      u32 c = hist[base+j];
      if(cum + c >= target){
        ctrl->T = (ctrl->b1 << 16) | (base+j);
        ctrl->candcnt = 0;
        break;
      }
      cum += c;
    }
  }
}

__global__ void k_collect(const u32* __restrict__ keys, Ctrl* ctrl, u64* __restrict__ cand){
  int i = blockIdx.x*256 + threadIdx.x;
  if(i >= NM) return;
  u32 k = keys[i];
  if(k >= ctrl->T){
    u32 p = atomicAdd(&ctrl->candcnt, 1u);
    if(p < (u32)CCAP) cand[p] = ((u64)(~k) << 32) | (u32)i;
  }
}

__global__ __launch_bounds__(1024) void k_sortsel(const u64* __restrict__ cand, const Ctrl* ctrl, int* __restrict__ idx){
  __shared__ u64 sm[CCAP];
  int t = threadIdx.x;
  u32 n = ctrl->candcnt; if(n > (u32)CCAP) n = CCAP;
  for(int i=t;i<CCAP;i+=1024) sm[i] = (i < (int)n) ? cand[i] : 0xFFFFFFFFFFFFFFFFull;
  __syncthreads();
  for(int k=2;k<=CCAP;k<<=1){
    for(int j=k>>1;j>0;j>>=1){
      for(int i=t;i<CCAP;i+=1024){
        int ixj = i ^ j;
        if(ixj > i){
          bool up = ((i & k) == 0);
          u64 a = sm[i], b = sm[ixj];
          if((a > b) == up){ sm[i] = b; sm[ixj] = a; }
        }
      }
      __syncthreads();
    }
  }
  if(t < KS) idx[t] = (int)(sm[t] & 0xFFFFFFFFu);
}

// ----------------- gathers + action MLP hidden -----------------
__global__ void k_gather(const int* __restrict__ idx,
                         const float* __restrict__ mv, const float* __restrict__ mnv,
                         const float* __restrict__ mrew,
                         const int* __restrict__ aim, const int* __restrict__ ait,
                         const float* __restrict__ amw1, const float* __restrict__ amb1,
                         const float* __restrict__ atw1, const float* __restrict__ atb1,
                         float* __restrict__ sel, float* __restrict__ outnext,
                         float* __restrict__ hm, float* __restrict__ ht,
                         float* __restrict__ rew, float* __restrict__ outrew){
  int k = blockIdx.x;
  int row = idx[k];
  const float* a = mv  + (size_t)row*HD;
  const float* b = mnv + (size_t)row*HD;
  for(int c=threadIdx.x;c<HD;c+=256){
    sel[(size_t)k*HD+c] = a[c];
    outnext[(size_t)k*HD+c] = b[c];
  }
  int am = aim[row], at = ait[row];
  for(int j=threadIdx.x;j<HD;j+=256){
    hm[(size_t)k*HD+j] = gelu_f(amw1[(size_t)j*9 + am] + amb1[j]);
    ht[(size_t)k*HD+j] = gelu_f(atw1[(size_t)j*4 + at] + atb1[j]);
  }
  if(threadIdx.x == 0){ float r = mrew[row]; rew[k] = r; outrew[k] = r; }
}

// ----------------- bf16 MFMA split-K GEMM: P[z] = A @ B^T (K-slice z) -----------------
// A: [M][K] fp32 row-major, B: [N][K] fp32 row-major. 64x64 tile, 4 waves (2x2 of 32x32), BK=32.
__global__ __launch_bounds__(256) void gemm_part(const float* __restrict__ A, const float* __restrict__ B,
        float* __restrict__ P, int M, int N, int K, int S, int nbm){
  // bijective XCD swizzle (m204): consecutive swz ids land on same XCD
  u32 nwg = gridDim.x;
  u32 orig = blockIdx.x;
  u32 q = nwg >> 3, r8 = nwg & 7;
  u32 xcd = orig & 7, loc = orig >> 3;
  u32 swz = (xcd < r8 ? xcd*(q+1) : r8*(q+1) + (xcd-r8)*q) + loc;
  int bm = (int)(swz % (u32)nbm) * 64;
  u32 tmp = swz / (u32)nbm;
  int z  = (int)(tmp % (u32)S);
  int bn = (int)(tmp / (u32)S) * 64;
  int Ks = K / S, kbeg = z*Ks;

  __shared__ short As[64*32];
  __shared__ short Bs[64*32];

  int t = threadIdx.x;
  int srow = t >> 2, sg = t & 3;
  int sgp = sg ^ ((srow >> 1) & 3);           // LDS k-group swizzle
  bool arow_ok = (bm + srow) < M;
  const float* ap = A + (size_t)(bm + srow)*K + kbeg + sg*8;
  const float* bp = B + (size_t)(bn + srow)*K + kbeg + sg*8;
  short* asw = &As[srow*32 + sgp*8];
  short* bsw = &Bs[srow*32 + sgp*8];

  int lane = t & 63, w = t >> 6;
  int wm = (w >> 1)*32, wn = (w & 1)*32;
  int lr = lane & 15, lg = lane >> 4;
  int ra0 = wm + lr, ra1 = ra0 + 16;
  int rb0 = wn + lr, rb1 = rb0 + 16;
  const bf16x8* pa0 = (const bf16x8*)&As[ra0*32 + (lg ^ ((ra0>>1)&3))*8];
  const bf16x8* pa1 = (const bf16x8*)&As[ra1*32 + (lg ^ ((ra1>>1)&3))*8];
  const bf16x8* pb0 = (const bf16x8*)&Bs[rb0*32 + (lg ^ ((rb0>>1)&3))*8];
  const bf16x8* pb1 = (const bf16x8*)&Bs[rb1*32 + (lg ^ ((rb1>>1)&3))*8];

  f32x4v acc00 = {0,0,0,0}, acc01 = {0,0,0,0}, acc10 = {0,0,0,0}, acc11 = {0,0,0,0};

  for(int kk = 0; kk < Ks; kk += 32){
    float4 va0 = {0,0,0,0}, va1 = {0,0,0,0};
    if(arow_ok){ va0 = *(const float4*)ap; va1 = *(const float4*)(ap+4); }
    float4 vb0 = *(const float4*)bp;
    float4 vb1 = *(const float4*)(bp+4);
    ap += 32; bp += 32;
    bf16x8 sa, sb;
    sa[0]=f2bf(va0.x); sa[1]=f2bf(va0.y); sa[2]=f2bf(va0.z); sa[3]=f2bf(va0.w);
    sa[4]=f2bf(va1.x); sa[5]=f2bf(va1.y); sa[6]=f2bf(va1.z); sa[7]=f2bf(va1.w);
    sb[0]=f2bf(vb0.x); sb[1]=f2bf(vb0.y); sb[2]=f2bf(vb0.z); sb[3]=f2bf(vb0.w);
    sb[4]=f2bf(vb1.x); sb[5]=f2bf(vb1.y); sb[6]=f2bf(vb1.z); sb[7]=f2bf(vb1.w);
    __syncthreads();
    *(bf16x8*)asw = sa;
    *(bf16x8*)bsw = sb;
    __syncthreads();
    bf16x8 a0 = *pa0, a1 = *pa1, b0 = *pb0, b1 = *pb1;
    acc00 = __builtin_amdgcn_mfma_f32_16x16x32_bf16(a0, b0, acc00, 0, 0, 0);
    acc01 = __builtin_amdgcn_mfma_f32_16x16x32_bf16(a0, b1, acc01, 0, 0, 0);
    acc10 = __builtin_amdgcn_mfma_f32_16x16x32_bf16(a1, b0, acc10, 0, 0, 0);
    acc11 = __builtin_amdgcn_mfma_f32_16x16x32_bf16(a1, b1, acc11, 0, 0, 0);
  }

  // C/D layout: col = lane&15, row = (lane>>4)*4 + reg
  size_t zbase = (size_t)z * (size_t)M;
  #pragma unroll
  for(int r=0;r<4;++r){
    int row0 = bm + wm + lg*4 + r;
    int row1 = row0 + 16;
    int c0 = bn + wn + lr, c1 = c0 + 16;
    if(row0 < M){
      P[(zbase+row0)*N + c0] = acc00[r];
      P[(zbase+row0)*N + c1] = acc01[r];
    }
    if(row1 < M){
      P[(zbase+row1)*N + c0] = acc10[r];
      P[(zbase+row1)*N + c1] = acc11[r];
    }
  }
}

// ----------------- split-K finish: C = act(sum_z P[z] + bias) (+res) -----------------
template<int ACT, bool RES>
__global__ void k_fin(const float* __restrict__ P, const float* __restrict__ bias,
                      const float* __restrict__ res, float* __restrict__ C,
                      int MN, int N, int S){
  int i = blockIdx.x*256 + threadIdx.x;
  if(i >= MN) return;
  float v = 0.f;
  for(int s=0;s<S;++s) v += P[(size_t)s*MN + i];
  v += bias[i % N];
  if(ACT == 1) v = gelu_f(v);
  if(RES) v += res[i];
  C[i] = v;
}

// ----------------- layernorm -----------------
__global__ void k_ln(const float* __restrict__ in, const float* __restrict__ w, const float* __restrict__ b,
                     float* __restrict__ outp){
  __shared__ float red[256];
  int row = blockIdx.x, t = threadIdx.x;
  const float* xr = in + (size_t)row*HD;
  float s = 0.f;
  for(int i=t;i<HD;i+=256) s += xr[i];
  red[t]=s; __syncthreads();
  for(int o=128;o>0;o>>=1){ if(t<o) red[t]+=red[t+o]; __syncthreads(); }
  float m = red[0] * (1.0f/HD);
  __syncthreads();
  float ss = 0.f;
  for(int i=t;i<HD;i+=256){ float d = xr[i]-m; ss += d*d; }
  red[t]=ss; __syncthreads();
  for(int o=128;o>0;o>>=1){ if(t<o) red[t]+=red[t+o]; __syncthreads(); }
  float var = red[0] * (1.0f/HD);
  float denom = sqrtf(var + 1e-5f);
  for(int i=t;i<HD;i+=256) outp[(size_t)row*HD+i] = (xr[i]-m)/denom * w[i] + b[i];
}

// ----------------- attention -----------------
__global__ void k_attn(const float* __restrict__ qkv, float* __restrict__ outp){
  __shared__ float qv[64];
  __shared__ float p[SQ];
  __shared__ float red[256];
  int q = blockIdx.x, h = blockIdx.y, t = threadIdx.x;
  if(t < 64) qv[t] = qkv[(size_t)q*3072 + h*64 + t];
  __syncthreads();
  int nk = q + 1;
  float lmax = -1e30f;
  for(int j=t;j<nk;j+=256){
    const float* kr = qkv + (size_t)j*3072 + 1024 + h*64;
    float d = 0.f;
    for(int c=0;c<64;++c) d += qv[c]*kr[c];
    d *= 0.125f;
    p[j] = d;
    lmax = fmaxf(lmax, d);
  }
  red[t] = lmax; __syncthreads();
  for(int o=128;o>0;o>>=1){ if(t<o) red[t] = fmaxf(red[t], red[t+o]); __syncthreads(); }
  float m = red[0];
  __syncthreads();
  float lsum = 0.f;
  for(int j=t;j<nk;j+=256){ float e = expf(p[j]-m); p[j] = e; lsum += e; }
  red[t] = lsum; __syncthreads();
  for(int o=128;o>0;o>>=1){ if(t<o) red[t] += red[t+o]; __syncthreads(); }
  float inv = 1.0f/red[0];
  __syncthreads();
  int d = t & 63, g = t >> 6;
  float acc = 0.f;
  for(int j=g;j<nk;j+=4) acc += p[j]*qkv[(size_t)j*3072 + 2048 + h*64 + d];
  red[t] = acc; __syncthreads();
  if(g == 0){
    float o4 = red[d] + red[64+d] + red[128+d] + red[192+d];
    outp[(size_t)q*HD + h*64 + d] = o4*inv;
  }
}

// ----------------- assembly / heads / outputs -----------------
__global__ void k_assemble(const float* __restrict__ start, const float* __restrict__ x,
                           const float* __restrict__ sel, const float* __restrict__ avm,
                           const float* __restrict__ avt, const float* __restrict__ pos,
                           float* __restrict__ vecs){
  int row = blockIdx.x;
  for(int j=threadIdx.x;j<HD;j+=256){
    float v;
    if(row == 0) v = start[j];
    else if(row == SQ-1) v = x[j];
    else if(row & 1) v = sel[(size_t)((row-1)>>1)*HD + j];
    else { int tt = (row-2)>>1; v = 0.5f*(avm[(size_t)tt*HD+j] + avt[(size_t)tt*HD+j]); }
    vecs[(size_t)row*HD + j] = v + pos[(size_t)row*HD + j];
  }
}

__global__ void k_vhin(const float* __restrict__ vecs, float* __restrict__ vhin){
  int r = blockIdx.x;
  const float* src = vecs + (size_t)(2*r+1)*HD;
  for(int j=threadIdx.x;j<HD;j+=256) vhin[(size_t)r*HD+j] = src[j];
}

__global__ void k_vp(const float* __restrict__ vhh, const float* __restrict__ w2,
                     const float* __restrict__ b2, float* __restrict__ vp){
  __shared__ float red[256];
  int r = blockIdx.x, t = threadIdx.x;
  float s = 0.f;
  for(int i=t;i<4096;i+=256) s += vhh[(size_t)r*4096+i]*w2[i];
  red[t]=s; __syncthreads();
  for(int o=128;o>0;o>>=1){ if(t<o) red[t]+=red[t+o]; __syncthreads(); }
  if(t == 0) vp[r] = red[0] + b2[0];
}

__global__ void k_outvecs(const float* __restrict__ vecs, float* __restrict__ outp){
  int i = blockIdx.x*256 + threadIdx.x;
  if(i < 257*HD) outp[i] = vecs[HD + i];
}

__global__ void k_outsmall(const float* __restrict__ vp, const float* __restrict__ rew, float* __restrict__ outp){
  int t = threadIdx.x;
  if(t == 0) outp[OUT_VP] = vp[KS];
  if(t < KS){
    float d = vp[t] - rew[t];
    outp[OUT_LOSS + t] = d*d;
    outp[OUT_REWO + t] = rew[t];
  }
}

extern "C" void kernel_launch(void* const* d_in, const int* in_sizes, int n_in,
                              void* d_out, int out_size, void* d_ws, size_t ws_size,
                              hipStream_t stream){
  const float* x     = (const float*)d_in[0];
  const float* mv    = (const float*)d_in[1];
  const float* mnv   = (const float*)d_in[2];
  const float* surp  = (const float*)d_in[3];
  const float* mrew  = (const float*)d_in[4];
  const float* noise = (const float*)d_in[5];
  const int*   aim   = (const int*)d_in[6];
  const int*   ait   = (const int*)d_in[7];
  const float* start = (const float*)d_in[8];
  const float* pos   = (const float*)d_in[9];
  const float* inW = (const float*)d_in[10]; const float* inB = (const float*)d_in[11];
  const float* oW  = (const float*)d_in[12]; const float* oB  = (const float*)d_in[13];
  const float* l1w = (const float*)d_in[14]; const float* l1b = (const float*)d_in[15];
  const float* l2w = (const float*)d_in[16]; const float* l2b = (const float*)d_in[17];
  const float* f1w = (const float*)d_in[18]; const float* f1b = (const float*)d_in[19];
  const float* f2w = (const float*)d_in[20]; const float* f2b = (const float*)d_in[21];
  const float* amw1= (const float*)d_in[22]; const float* amb1= (const float*)d_in[23];
  const float* amw2= (const float*)d_in[24]; const float* amb2= (const float*)d_in[25];
  const float* atw1= (const float*)d_in[26]; const float* atb1= (const float*)d_in[27];
  const float* atw2= (const float*)d_in[28]; const float* atb2= (const float*)d_in[29];
  const float* vw1 = (const float*)d_in[30]; const float* vb1 = (const float*)d_in[31];
  const float* vw2 = (const float*)d_in[32]; const float* vb2 = (const float*)d_in[33];

  float* out = (float*)d_out;
  char* ws = (char*)d_ws;
  u32*  keys = (u32*)(ws+OFF_KEYS);
  u32*  hist = (u32*)(ws+OFF_HIST);
  u32*  pref = (u32*)(ws+OFF_PREF);
  u32*  cnt  = (u32*)(ws+OFF_CNT);
  u32*  lo   = (u32*)(ws+OFF_LO);
  float* r0  = (float*)(ws+OFF_R0);
  float* r1  = (float*)(ws+OFF_R1);
  float* r2  = (float*)(ws+OFF_R2);
  u64*  cand = (u64*)(ws+OFF_CAND);
  Ctrl* ctrl = (Ctrl*)(ws+OFF_CTRL);
  int*  idxb = (int*)(ws+OFF_IDX);
  float* xn  = (float*)(ws+OFF_XN);
  float* simv= (float*)(ws+OFF_SIM);
  float* sel = (float*)(ws+OFF_SEL);
  float* hm  = (float*)(ws+OFF_HM);
  float* ht  = (float*)(ws+OFF_HT);
  float* avm = (float*)(ws+OFF_AVM);
  float* avt = (float*)(ws+OFF_AVT);
  float* rew = (float*)(ws+OFF_REW);
  float* vecs= (float*)(ws+OFF_VECS);
  float* lnb = (float*)(ws+OFF_LNB);
  float* qkvb= (float*)(ws+OFF_QKV);
  float* attn= (float*)(ws+OFF_ATT);
  float* ffh = (float*)(ws+OFF_FFH);
  float* vhin= (float*)(ws+OFF_VHIN);
  float* vhh = (float*)(ws+OFF_VHH);
  float* vp  = (float*)(ws+OFF_VP);
  float* part= (float*)(ws+OFF_PART);

  dim3 b256(256);
  int gN = NM/256;

  // ---- scoring ----
  hipLaunchKernelGGL(k_xnorm, dim3(1), b256, 0, stream, x, xn);
  hipLaunchKernelGGL(k_sim2, dim3(NM/4), b256, 0, stream, mv, xn, simv);

  const float* rank_src[3] = { surp, simv, noise };
  float* rank_dst[3] = { r0, r1, r2 };
  for(int a=0;a<3;++a){
    (void)hipMemsetAsync(hist, 0, (size_t)NBIN*4, stream);
    (void)hipMemsetAsync(cnt,  0, (size_t)NBIN*4, stream);
    hipLaunchKernelGGL(k_keyhist, dim3(gN), b256, 0, stream, rank_src[a], keys, hist);
    hipLaunchKernelGGL(k_scan, dim3(1), dim3(1024), 0, stream, hist, pref);
    hipLaunchKernelGGL(k_scatter, dim3(gN), b256, 0, stream, keys, pref, cnt, lo);
    hipLaunchKernelGGL(k_rank, dim3(gN), b256, 0, stream, keys, pref, lo, rank_dst[a]);
  }

  (void)hipMemsetAsync(hist, 0, (size_t)NBIN*4, stream);
  hipLaunchKernelGGL(k_score, dim3(gN), b256, 0, stream, r0, r1, r2, keys, hist);
  hipLaunchKernelGGL(k_sel1, dim3(1), dim3(1024), 0, stream, hist, ctrl);
  (void)hipMemsetAsync(cnt, 0, (size_t)NBIN*4, stream);
  hipLaunchKernelGGL(k_histlo, dim3(gN), b256, 0, stream, keys, ctrl, cnt);
  hipLaunchKernelGGL(k_sel2, dim3(1), dim3(1024), 0, stream, cnt, ctrl);
  hipLaunchKernelGGL(k_collect, dim3(gN), b256, 0, stream, keys, ctrl, cand);
  hipLaunchKernelGGL(k_sortsel, dim3(1), dim3(1024), 0, stream, cand, ctrl, idxb);

  // ---- GEMM helper (split-K MFMA + finish) ----
  auto gemm = [&](const float* A, const float* Bw, const float* bias, const float* res,
                  float* C, int M, int N, int K, int S, int act){
    int nbm = (M + 63) / 64, nbn = N / 64;
    int nwg = nbm * nbn * S;
    hipLaunchKernelGGL(gemm_part, dim3(nwg), b256, 0, stream, A, Bw, part, M, N, K, S, nbm);
    int MN = M * N;
    int g = (MN + 255) / 256;
    if(act == 1)       hipLaunchKernelGGL((k_fin<1,false>), dim3(g), b256, 0, stream, part, bias, res, C, MN, N, S);
    else if(res)       hipLaunchKernelGGL((k_fin<0,true>),  dim3(g), b256, 0, stream, part, bias, res, C, MN, N, S);
    else               hipLaunchKernelGGL((k_fin<0,false>), dim3(g), b256, 0, stream, part, bias, res, C, MN, N, S);
  };

  // ---- gathers + action MLP ----
  hipLaunchKernelGGL(k_gather, dim3(KS), b256, 0, stream, idxb, mv, mnv, mrew, aim, ait,
                     amw1, amb1, atw1, atb1, sel, out + OUT_NEXT, hm, ht, rew, out + OUT_REWO);
  gemm(hm, amw2, amb2, nullptr, avm, KS, HD, HD, 4, 0);
  gemm(ht, atw2, atb2, nullptr, avt, KS, HD, HD, 4, 0);
  hipLaunchKernelGGL(k_assemble, dim3(SQ), b256, 0, stream, start, x, sel, avm, avt, pos, vecs);

  // ---- transformer ----
  for(int l=0;l<NL;++l){
    hipLaunchKernelGGL(k_ln, dim3(SQ), b256, 0, stream, vecs, l1w + (size_t)l*HD, l1b + (size_t)l*HD, lnb);
    gemm(lnb, inW + (size_t)l*3*HD*HD, inB + (size_t)l*3*HD, nullptr, qkvb, SQ, 3*HD, HD, 2, 0);
    hipLaunchKernelGGL(k_attn, dim3(SQ, NH_), b256, 0, stream, qkvb, attn);
    gemm(attn, oW + (size_t)l*HD*HD, oB + (size_t)l*HD, vecs, vecs, SQ, HD, HD, 2, 0);
    hipLaunchKernelGGL(k_ln, dim3(SQ), b256, 0, stream, vecs, l2w + (size_t)l*HD, l2b + (size_t)l*HD, lnb);
    gemm(lnb, f1w + (size_t)l*4*HD*HD, f1b + (size_t)l*4*HD, nullptr, ffh, SQ, 4*HD, HD, 2, 1);
    gemm(ffh, f2w + (size_t)l*HD*4*HD, f2b + (size_t)l*HD, vecs, vecs, SQ, HD, 4*HD, 8, 0);
  }

  // ---- value head + outputs ----
  hipLaunchKernelGGL(k_vhin, dim3(KS+1), b256, 0, stream, vecs, vhin);
  gemm(vhin, vw1, vb1, nullptr, vhh, KS+1, 4*HD, HD, 2, 1);
  hipLaunchKernelGGL(k_vp, dim3(KS+1), b256, 0, stream, vhh, vw2, vb2, vp);
  hipLaunchKernelGGL(k_outvecs, dim3(257*HD/256), b256, 0, stream, vecs, out);
  hipLaunchKernelGGL(k_outsmall, dim3(1), b256, 0, stream, vp, rew, out);
}

// Round 4
// 1151.793 us; speedup vs baseline: 3.5105x; 1.0324x over previous
//
#include <hip/hip_runtime.h>
#include <math.h>
#include <stdint.h>

typedef unsigned int u32;
typedef unsigned long long u64;

#define NM   65536
#define HD   1024
#define KS   128
#define SQ   258
#define NH_  16
#define NL   4
#define NBIN 65536
#define CCAP 1024

using bf16x8 = __attribute__((ext_vector_type(8))) short;
using f32x4v = __attribute__((ext_vector_type(4))) float;

struct Ctrl { u32 b1, above1, T, candcnt; };

static constexpr size_t A256(size_t x){ return (x + 255) & ~(size_t)255; }

// ---- zeroed-at-launch region (ONE memset) ----
constexpr size_t OFF_H3   = 0;                                  // 3*NBIN u32
constexpr size_t OFF_C3   = OFF_H3 + (size_t)3*NBIN*4;          // 3*NBIN u32
constexpr size_t OFF_HS   = OFF_C3 + (size_t)3*NBIN*4;          // NBIN u32
constexpr size_t OFF_CS   = OFF_HS + (size_t)NBIN*4;            // NBIN u32
constexpr size_t ZERO_BYTES = OFF_CS + (size_t)NBIN*4;          // 2 MB
// ---- rest ----
constexpr size_t OFF_P3   = A256(ZERO_BYTES);                       // 3*(NBIN+1) u32
constexpr size_t OFF_K3   = A256(OFF_P3 + (size_t)3*(NBIN+1)*4);    // 3*NM u32
constexpr size_t OFF_L3   = A256(OFF_K3 + (size_t)3*NM*4);          // 3*NM u32
constexpr size_t OFF_R3   = A256(OFF_L3 + (size_t)3*NM*4);          // 3*NM f32
constexpr size_t OFF_KSC  = A256(OFF_R3 + (size_t)3*NM*4);          // NM u32 (score keys)
constexpr size_t OFF_CAND = A256(OFF_KSC + (size_t)NM*4);
constexpr size_t OFF_CTRL = A256(OFF_CAND + (size_t)CCAP*8);
constexpr size_t OFF_IDX  = A256(OFF_CTRL + 256);
constexpr size_t OFF_SIM  = A256(OFF_IDX  + (size_t)KS*4);
constexpr size_t OFF_SEL  = A256(OFF_SIM  + (size_t)NM*4);
constexpr size_t OFF_HM   = A256(OFF_SEL  + (size_t)KS*HD*4);
constexpr size_t OFF_HT   = A256(OFF_HM   + (size_t)KS*HD*4);
constexpr size_t OFF_AVM  = A256(OFF_HT   + (size_t)KS*HD*4);
constexpr size_t OFF_AVT  = A256(OFF_AVM  + (size_t)KS*HD*4);
constexpr size_t OFF_REW  = A256(OFF_AVT  + (size_t)KS*HD*4);
constexpr size_t OFF_VECS = A256(OFF_REW  + (size_t)KS*4);
constexpr size_t OFF_LNB  = A256(OFF_VECS + (size_t)SQ*HD*4);
constexpr size_t OFF_QKV  = A256(OFF_LNB  + (size_t)SQ*HD*4);
constexpr size_t OFF_ATT  = A256(OFF_QKV  + (size_t)SQ*3*HD*4);
constexpr size_t OFF_FFH  = A256(OFF_ATT  + (size_t)SQ*HD*4);
constexpr size_t OFF_VHIN = A256(OFF_FFH  + (size_t)SQ*4*HD*4);
constexpr size_t OFF_VHH  = A256(OFF_VHIN + (size_t)129*HD*4);
constexpr size_t OFF_VP   = A256(OFF_VHH  + (size_t)129*4096*4);
constexpr size_t OFF_PART = A256(OFF_VP   + 256);   // max S*M*N*4 ~ 8.5 MB

// output layout (floats)
constexpr int OUT_NEXT = 257*HD;
constexpr int OUT_VP   = OUT_NEXT + KS*HD;
constexpr int OUT_LOSS = OUT_VP + 1;
constexpr int OUT_REWO = OUT_LOSS + KS;

__device__ __forceinline__ float gelu_f(float v){
  return 0.5f*v*(1.0f + erff(v*0.70710678118654752440f));
}

__device__ __forceinline__ short f2bf(float f){
  u32 b = __float_as_uint(f);
  return (short)((b + 0x7FFFu + ((b >> 16) & 1u)) >> 16);
}

// ----------------- scoring: fused xnorm + sim -----------------
__global__ __launch_bounds__(256) void k_sim2(const float* __restrict__ mv, const float* __restrict__ x, float* __restrict__ sim){
  __shared__ float xs[HD];
  __shared__ float red[256];
  int t = threadIdx.x;
  float s = 0.f;
  for(int i=t;i<HD;i+=256){ float v=x[i]; s += v*v; }
  red[t]=s; __syncthreads();
  for(int o=128;o>0;o>>=1){ if(t<o) red[t]+=red[t+o]; __syncthreads(); }
  float nrm = fmaxf(sqrtf(red[0]), 1e-8f);
  for(int i=t;i<HD;i+=256) xs[i] = x[i]/nrm;
  __syncthreads();
  int lane = t & 63, w = t >> 6;
  int row = blockIdx.x*4 + w;
  const float4* p = (const float4*)(mv + (size_t)row*HD);
  const float4* q = (const float4*)xs;
  float d=0.f, ss=0.f;
  #pragma unroll
  for(int r=0;r<4;++r){
    float4 v = p[lane + 64*r]; float4 u = q[lane + 64*r];
    d  += v.x*u.x + v.y*u.y + v.z*u.z + v.w*u.w;
    ss += v.x*v.x + v.y*v.y + v.z*v.z + v.w*v.w;
  }
  for(int off=32;off>0;off>>=1){ d += __shfl_xor(d,off,64); ss += __shfl_xor(ss,off,64); }
  if(lane==0) sim[row] = d / fmaxf(sqrtf(ss),1e-8f);
}

// ----------------- tie-aware ranking (3 arrays fused) -----------------
__global__ void k_keyhist3(const float* __restrict__ s0, const float* __restrict__ s1, const float* __restrict__ s2,
                           u32* __restrict__ keys3, u32* __restrict__ hist3){
  int i = blockIdx.x*256 + threadIdx.x;
  if(i >= NM) return;
  const float* srcs[3] = { s0, s1, s2 };
  #pragma unroll
  for(int a=0;a<3;++a){
    u32 b = __float_as_uint(srcs[a][i]);
    u32 k = (b >> 31) ? ~b : (b | 0x80000000u);
    keys3[(size_t)a*NM + i] = k;
    atomicAdd(&hist3[(size_t)a*NBIN + (k >> 16)], 1u);
  }
}

__global__ __launch_bounds__(1024) void k_scan3(const u32* __restrict__ hist3, u32* __restrict__ pref3){
  __shared__ u32 part[1024];
  const u32* hist = hist3 + (size_t)blockIdx.x*NBIN;
  u32* prefix = pref3 + (size_t)blockIdx.x*(NBIN+1);
  int t = threadIdx.x;
  u32 base = t*64, s = 0;
  for(int j=0;j<64;++j) s += hist[base+j];
  part[t] = s; __syncthreads();
  for(int off=1;off<1024;off<<=1){
    u32 v = (t >= off) ? part[t-off] : 0u;
    __syncthreads();
    part[t] += v;
    __syncthreads();
  }
  u32 run = part[t] - s;
  for(int j=0;j<64;++j){ prefix[base+j] = run; run += hist[base+j]; }
  if(t == 1023) prefix[NBIN] = run;
}

__global__ void k_scatter3(const u32* __restrict__ keys3, const u32* __restrict__ pref3,
                           u32* __restrict__ cnt3, u32* __restrict__ lo3){
  int i = blockIdx.x*256 + threadIdx.x;
  if(i >= NM) return;
  #pragma unroll
  for(int a=0;a<3;++a){
    u32 k = keys3[(size_t)a*NM + i];
    u32 b = k >> 16;
    u32 pos = pref3[(size_t)a*(NBIN+1) + b] + atomicAdd(&cnt3[(size_t)a*NBIN + b], 1u);
    lo3[(size_t)a*NM + pos] = k & 0xFFFFu;
  }
}

__global__ void k_rank3(const u32* __restrict__ keys3, const u32* __restrict__ pref3,
                        const u32* __restrict__ lo3, float* __restrict__ r3){
  int i = blockIdx.x*256 + threadIdx.x;
  if(i >= NM) return;
  #pragma unroll
  for(int a=0;a<3;++a){
    u32 k = keys3[(size_t)a*NM + i];
    u32 b = k >> 16, my = k & 0xFFFFu;
    const u32* pref = pref3 + (size_t)a*(NBIN+1);
    const u32* lo = lo3 + (size_t)a*NM;
    u32 s = pref[b], e = pref[b+1];
    u32 nl = 0, ne = 0;
    for(u32 j=s;j<e;++j){ u32 u = lo[j]; nl += (u < my); ne += (u == my); }
    u32 left = s + nl, right = left + ne;
    r3[(size_t)a*NM + i] = (float)(left + right - 1) * (1.0f/131072.0f);
  }
}

__global__ void k_score(const float* __restrict__ r3, u32* __restrict__ keys, u32* __restrict__ hist){
  int i = blockIdx.x*256 + threadIdx.x;
  if(i >= NM) return;
  float a = r3[i], b = r3[NM+i], c = r3[2*NM+i];
  float s = __fadd_rn(__fadd_rn(__fmul_rn(a,a), __fmul_rn(b,b)), __fmul_rn(c,c));
  u32 k = __float_as_uint(s);
  keys[i] = k;
  atomicAdd(&hist[k >> 16], 1u);
}

// ----------------- top-k select -----------------
__global__ __launch_bounds__(1024) void k_sel1(const u32* __restrict__ hist, Ctrl* ctrl){
  __shared__ u32 part[1024];
  int t = threadIdx.x;
  u32 base = t*64, s = 0;
  for(int j=0;j<64;++j) s += hist[base+j];
  part[t] = s; __syncthreads();
  for(int off=1;off<1024;off<<=1){
    u32 v = (t+off < 1024) ? part[t+off] : 0u;
    __syncthreads();
    part[t] += v;
    __syncthreads();
  }
  u32 above = part[t] - s;
  if(above < (u32)KS && above + s >= (u32)KS){
    u32 cum = above;
    for(int j=63;j>=0;--j){
      u32 c = hist[base+j];
      if(cum + c >= (u32)KS){ ctrl->b1 = base+j; ctrl->above1 = cum; break; }
      cum += c;
    }
  }
}

__global__ void k_histlo(const u32* __restrict__ keys, const Ctrl* ctrl, u32* __restrict__ h){
  int i = blockIdx.x*256 + threadIdx.x;
  if(i >= NM) return;
  u32 k = keys[i];
  if((k >> 16) == ctrl->b1) atomicAdd(&h[k & 0xFFFFu], 1u);
}

__global__ __launch_bounds__(1024) void k_sel2(const u32* __restrict__ hist, Ctrl* ctrl){
  __shared__ u32 part[1024];
  int t = threadIdx.x;
  u32 target = (u32)KS - ctrl->above1;
  u32 base = t*64, s = 0;
  for(int j=0;j<64;++j) s += hist[base+j];
  part[t] = s; __syncthreads();
  for(int off=1;off<1024;off<<=1){
    u32 v = (t+off < 1024) ? part[t+off] : 0u;
    __syncthreads();
    part[t] += v;
    __syncthreads();
  }
  u32 above = part[t] - s;
  if(above < target && above + s >= target){
    u32 cum = above;
    for(int j=63;j>=0;--j){
      u32 c = hist[base+j];
      if(cum + c >= target){
        ctrl->T = (ctrl->b1 << 16) | (base+j);
        ctrl->candcnt = 0;
        break;
      }
      cum += c;
    }
  }
}

__global__ void k_collect(const u32* __restrict__ keys, Ctrl* ctrl, u64* __restrict__ cand){
  int i = blockIdx.x*256 + threadIdx.x;
  if(i >= NM) return;
  u32 k = keys[i];
  if(k >= ctrl->T){
    u32 p = atomicAdd(&ctrl->candcnt, 1u);
    if(p < (u32)CCAP) cand[p] = ((u64)(~k) << 32) | (u32)i;
  }
}

__global__ __launch_bounds__(1024) void k_sortsel(const u64* __restrict__ cand, const Ctrl* ctrl, int* __restrict__ idx){
  __shared__ u64 sm[CCAP];
  int t = threadIdx.x;
  u32 n = ctrl->candcnt; if(n > (u32)CCAP) n = CCAP;
  if(t < CCAP) sm[t] = (t < (int)n) ? cand[t] : 0xFFFFFFFFFFFFFFFFull;
  __syncthreads();
  for(int k=2;k<=CCAP;k<<=1){
    for(int j=k>>1;j>0;j>>=1){
      if(t < CCAP){
        int ixj = t ^ j;
        if(ixj > t){
          bool up = ((t & k) == 0);
          u64 a = sm[t], b = sm[ixj];
          if((a > b) == up){ sm[t] = b; sm[ixj] = a; }
        }
      }
      __syncthreads();
    }
  }
  if(t < KS) idx[t] = (int)(sm[t] & 0xFFFFFFFFu);
}

// ----------------- gathers + action MLP hidden -----------------
__global__ void k_gather(const int* __restrict__ idx,
                         const float* __restrict__ mv, const float* __restrict__ mnv,
                         const float* __restrict__ mrew,
                         const int* __restrict__ aim, const int* __restrict__ ait,
                         const float* __restrict__ amw1, const float* __restrict__ amb1,
                         const float* __restrict__ atw1, const float* __restrict__ atb1,
                         float* __restrict__ sel, float* __restrict__ outnext,
                         float* __restrict__ hm, float* __restrict__ ht,
                         float* __restrict__ rew, float* __restrict__ outrew){
  int k = blockIdx.x;
  int row = idx[k];
  const float* a = mv  + (size_t)row*HD;
  const float* b = mnv + (size_t)row*HD;
  for(int c=threadIdx.x;c<HD;c+=256){
    sel[(size_t)k*HD+c] = a[c];
    outnext[(size_t)k*HD+c] = b[c];
  }
  int am = aim[row], at = ait[row];
  for(int j=threadIdx.x;j<HD;j+=256){
    hm[(size_t)k*HD+j] = gelu_f(amw1[(size_t)j*9 + am] + amb1[j]);
    ht[(size_t)k*HD+j] = gelu_f(atw1[(size_t)j*4 + at] + atb1[j]);
  }
  if(threadIdx.x == 0){ float r = mrew[row]; rew[k] = r; outrew[k] = r; }
}

// ----------------- bf16 MFMA GEMM (split-K or direct) -----------------
// A: [M][K] fp32, B: [N][K] fp32. 64x64 tile, 4 waves (2x2 of 32x32), BK=32.
// DIRECT (S==1): C = act(A@B^T + bias) (+res). else: P[z] = partial.
template<int ACT, bool RES, bool DIRECT>
__global__ __launch_bounds__(256) void gemm_part(const float* __restrict__ A, const float* __restrict__ B,
        const float* __restrict__ bias, const float* __restrict__ res,
        float* __restrict__ P, int M, int N, int K, int S, int nbm){
  u32 nwg = gridDim.x;
  u32 orig = blockIdx.x;
  u32 q = nwg >> 3, r8 = nwg & 7;
  u32 xcd = orig & 7, loc = orig >> 3;
  u32 swz = (xcd < r8 ? xcd*(q+1) : r8*(q+1) + (xcd-r8)*q) + loc;
  int bm = (int)(swz % (u32)nbm) * 64;
  u32 tmp = swz / (u32)nbm;
  int z  = DIRECT ? 0 : (int)(tmp % (u32)S);
  int bn = DIRECT ? (int)tmp * 64 : (int)(tmp / (u32)S) * 64;
  int Ks = K / S, kbeg = z*Ks;

  __shared__ short As[64*32];
  __shared__ short Bs[64*32];

  int t = threadIdx.x;
  int srow = t >> 2, sg = t & 3;
  int sgp = sg ^ ((srow >> 1) & 3);
  bool arow_ok = (bm + srow) < M;
  const float* ap = A + (size_t)(bm + srow)*K + kbeg + sg*8;
  const float* bp = B + (size_t)(bn + srow)*K + kbeg + sg*8;
  short* asw = &As[srow*32 + sgp*8];
  short* bsw = &Bs[srow*32 + sgp*8];

  int lane = t & 63, w = t >> 6;
  int wm = (w >> 1)*32, wn = (w & 1)*32;
  int lr = lane & 15, lg = lane >> 4;
  int ra0 = wm + lr, ra1 = ra0 + 16;
  int rb0 = wn + lr, rb1 = rb0 + 16;
  const bf16x8* pa0 = (const bf16x8*)&As[ra0*32 + (lg ^ ((ra0>>1)&3))*8];
  const bf16x8* pa1 = (const bf16x8*)&As[ra1*32 + (lg ^ ((ra1>>1)&3))*8];
  const bf16x8* pb0 = (const bf16x8*)&Bs[rb0*32 + (lg ^ ((rb0>>1)&3))*8];
  const bf16x8* pb1 = (const bf16x8*)&Bs[rb1*32 + (lg ^ ((rb1>>1)&3))*8];

  f32x4v acc00 = {0,0,0,0}, acc01 = {0,0,0,0}, acc10 = {0,0,0,0}, acc11 = {0,0,0,0};

  for(int kk = 0; kk < Ks; kk += 32){
    float4 va0 = {0,0,0,0}, va1 = {0,0,0,0};
    if(arow_ok){ va0 = *(const float4*)ap; va1 = *(const float4*)(ap+4); }
    float4 vb0 = *(const float4*)bp;
    float4 vb1 = *(const float4*)(bp+4);
    ap += 32; bp += 32;
    bf16x8 sa, sb;
    sa[0]=f2bf(va0.x); sa[1]=f2bf(va0.y); sa[2]=f2bf(va0.z); sa[3]=f2bf(va0.w);
    sa[4]=f2bf(va1.x); sa[5]=f2bf(va1.y); sa[6]=f2bf(va1.z); sa[7]=f2bf(va1.w);
    sb[0]=f2bf(vb0.x); sb[1]=f2bf(vb0.y); sb[2]=f2bf(vb0.z); sb[3]=f2bf(vb0.w);
    sb[4]=f2bf(vb1.x); sb[5]=f2bf(vb1.y); sb[6]=f2bf(vb1.z); sb[7]=f2bf(vb1.w);
    __syncthreads();
    *(bf16x8*)asw = sa;
    *(bf16x8*)bsw = sb;
    __syncthreads();
    bf16x8 a0 = *pa0, a1 = *pa1, b0 = *pb0, b1 = *pb1;
    acc00 = __builtin_amdgcn_mfma_f32_16x16x32_bf16(a0, b0, acc00, 0, 0, 0);
    acc01 = __builtin_amdgcn_mfma_f32_16x16x32_bf16(a0, b1, acc01, 0, 0, 0);
    acc10 = __builtin_amdgcn_mfma_f32_16x16x32_bf16(a1, b0, acc10, 0, 0, 0);
    acc11 = __builtin_amdgcn_mfma_f32_16x16x32_bf16(a1, b1, acc11, 0, 0, 0);
  }

  size_t zbase = (size_t)z * (size_t)M;
  #pragma unroll
  for(int r=0;r<4;++r){
    int row0 = bm + wm + lg*4 + r;
    int row1 = row0 + 16;
    int c0 = bn + wn + lr, c1 = c0 + 16;
    if(DIRECT){
      if(row0 < M){
        float v0 = acc00[r] + bias[c0], v1 = acc01[r] + bias[c1];
        if(ACT == 1){ v0 = gelu_f(v0); v1 = gelu_f(v1); }
        if(RES){ v0 += res[(size_t)row0*N + c0]; v1 += res[(size_t)row0*N + c1]; }
        P[(size_t)row0*N + c0] = v0; P[(size_t)row0*N + c1] = v1;
      }
      if(row1 < M){
        float v0 = acc10[r] + bias[c0], v1 = acc11[r] + bias[c1];
        if(ACT == 1){ v0 = gelu_f(v0); v1 = gelu_f(v1); }
        if(RES){ v0 += res[(size_t)row1*N + c0]; v1 += res[(size_t)row1*N + c1]; }
        P[(size_t)row1*N + c0] = v0; P[(size_t)row1*N + c1] = v1;
      }
    } else {
      if(row0 < M){
        P[(zbase+row0)*N + c0] = acc00[r];
        P[(zbase+row0)*N + c1] = acc01[r];
      }
      if(row1 < M){
        P[(zbase+row1)*N + c0] = acc10[r];
        P[(zbase+row1)*N + c1] = acc11[r];
      }
    }
  }
}

// ----------------- split-K finish -----------------
template<int ACT, bool RES>
__global__ void k_fin(const float* __restrict__ P, const float* __restrict__ bias,
                      const float* __restrict__ res, float* __restrict__ C,
                      int MN, int N, int S){
  int i = blockIdx.x*256 + threadIdx.x;
  if(i >= MN) return;
  float v = 0.f;
  for(int s=0;s<S;++s) v += P[(size_t)s*MN + i];
  v += bias[i % N];
  if(ACT == 1) v = gelu_f(v);
  if(RES) v += res[i];
  C[i] = v;
}

// ----------------- layernorm -----------------
__global__ void k_ln(const float* __restrict__ in, const float* __restrict__ w, const float* __restrict__ b,
                     float* __restrict__ outp){
  __shared__ float red[256];
  int row = blockIdx.x, t = threadIdx.x;
  const float* xr = in + (size_t)row*HD;
  float s = 0.f;
  for(int i=t;i<HD;i+=256) s += xr[i];
  red[t]=s; __syncthreads();
  for(int o=128;o>0;o>>=1){ if(t<o) red[t]+=red[t+o]; __syncthreads(); }
  float m = red[0] * (1.0f/HD);
  __syncthreads();
  float ss = 0.f;
  for(int i=t;i<HD;i+=256){ float d = xr[i]-m; ss += d*d; }
  red[t]=ss; __syncthreads();
  for(int o=128;o>0;o>>=1){ if(t<o) red[t]+=red[t+o]; __syncthreads(); }
  float var = red[0] * (1.0f/HD);
  float denom = sqrtf(var + 1e-5f);
  for(int i=t;i<HD;i+=256) outp[(size_t)row*HD+i] = (xr[i]-m)/denom * w[i] + b[i];
}

// ----------------- attention -----------------
__global__ void k_attn(const float* __restrict__ qkv, float* __restrict__ outp){
  __shared__ float qv[64];
  __shared__ float p[SQ];
  __shared__ float red[256];
  int q = blockIdx.x, h = blockIdx.y, t = threadIdx.x;
  if(t < 64) qv[t] = qkv[(size_t)q*3072 + h*64 + t];
  __syncthreads();
  int nk = q + 1;
  float lmax = -1e30f;
  for(int j=t;j<nk;j+=256){
    const float* kr = qkv + (size_t)j*3072 + 1024 + h*64;
    float d = 0.f;
    for(int c=0;c<64;++c) d += qv[c]*kr[c];
    d *= 0.125f;
    p[j] = d;
    lmax = fmaxf(lmax, d);
  }
  red[t] = lmax; __syncthreads();
  for(int o=128;o>0;o>>=1){ if(t<o) red[t] = fmaxf(red[t], red[t+o]); __syncthreads(); }
  float m = red[0];
  __syncthreads();
  float lsum = 0.f;
  for(int j=t;j<nk;j+=256){ float e = expf(p[j]-m); p[j] = e; lsum += e; }
  red[t] = lsum; __syncthreads();
  for(int o=128;o>0;o>>=1){ if(t<o) red[t] += red[t+o]; __syncthreads(); }
  float inv = 1.0f/red[0];
  __syncthreads();
  int d = t & 63, g = t >> 6;
  float acc = 0.f;
  for(int j=g;j<nk;j+=4) acc += p[j]*qkv[(size_t)j*3072 + 2048 + h*64 + d];
  red[t] = acc; __syncthreads();
  if(g == 0){
    float o4 = red[d] + red[64+d] + red[128+d] + red[192+d];
    outp[(size_t)q*HD + h*64 + d] = o4*inv;
  }
}

// ----------------- assembly / heads / outputs -----------------
__global__ void k_assemble(const float* __restrict__ start, const float* __restrict__ x,
                           const float* __restrict__ sel, const float* __restrict__ avm,
                           const float* __restrict__ avt, const float* __restrict__ pos,
                           float* __restrict__ vecs){
  int row = blockIdx.x;
  for(int j=threadIdx.x;j<HD;j+=256){
    float v;
    if(row == 0) v = start[j];
    else if(row == SQ-1) v = x[j];
    else if(row & 1) v = sel[(size_t)((row-1)>>1)*HD + j];
    else { int tt = (row-2)>>1; v = 0.5f*(avm[(size_t)tt*HD+j] + avt[(size_t)tt*HD+j]); }
    vecs[(size_t)row*HD + j] = v + pos[(size_t)row*HD + j];
  }
}

__global__ void k_vhin(const float* __restrict__ vecs, float* __restrict__ vhin){
  int r = blockIdx.x;
  const float* src = vecs + (size_t)(2*r+1)*HD;
  for(int j=threadIdx.x;j<HD;j+=256) vhin[(size_t)r*HD+j] = src[j];
}

__global__ void k_vp(const float* __restrict__ vhh, const float* __restrict__ w2,
                     const float* __restrict__ b2, float* __restrict__ vp){
  __shared__ float red[256];
  int r = blockIdx.x, t = threadIdx.x;
  float s = 0.f;
  for(int i=t;i<4096;i+=256) s += vhh[(size_t)r*4096+i]*w2[i];
  red[t]=s; __syncthreads();
  for(int o=128;o>0;o>>=1){ if(t<o) red[t]+=red[t+o]; __syncthreads(); }
  if(t == 0) vp[r] = red[0] + b2[0];
}

__global__ void k_outvecs(const float* __restrict__ vecs, float* __restrict__ outp){
  int i = blockIdx.x*256 + threadIdx.x;
  if(i < 257*HD) outp[i] = vecs[HD + i];
}

__global__ void k_outsmall(const float* __restrict__ vp, const float* __restrict__ rew, float* __restrict__ outp){
  int t = threadIdx.x;
  if(t == 0) outp[OUT_VP] = vp[KS];
  if(t < KS){
    float d = vp[t] - rew[t];
    outp[OUT_LOSS + t] = d*d;
    outp[OUT_REWO + t] = rew[t];
  }
}

extern "C" void kernel_launch(void* const* d_in, const int* in_sizes, int n_in,
                              void* d_out, int out_size, void* d_ws, size_t ws_size,
                              hipStream_t stream){
  const float* x     = (const float*)d_in[0];
  const float* mv    = (const float*)d_in[1];
  const float* mnv   = (const float*)d_in[2];
  const float* surp  = (const float*)d_in[3];
  const float* mrew  = (const float*)d_in[4];
  const float* noise = (const float*)d_in[5];
  const int*   aim   = (const int*)d_in[6];
  const int*   ait   = (const int*)d_in[7];
  const float* start = (const float*)d_in[8];
  const float* pos   = (const float*)d_in[9];
  const float* inW = (const float*)d_in[10]; const float* inB = (const float*)d_in[11];
  const float* oW  = (const float*)d_in[12]; const float* oB  = (const float*)d_in[13];
  const float* l1w = (const float*)d_in[14]; const float* l1b = (const float*)d_in[15];
  const float* l2w = (const float*)d_in[16]; const float* l2b = (const float*)d_in[17];
  const float* f1w = (const float*)d_in[18]; const float* f1b = (const float*)d_in[19];
  const float* f2w = (const float*)d_in[20]; const float* f2b = (const float*)d_in[21];
  const float* amw1= (const float*)d_in[22]; const float* amb1= (const float*)d_in[23];
  const float* amw2= (const float*)d_in[24]; const float* amb2= (const float*)d_in[25];
  const float* atw1= (const float*)d_in[26]; const float* atb1= (const float*)d_in[27];
  const float* atw2= (const float*)d_in[28]; const float* atb2= (const float*)d_in[29];
  const float* vw1 = (const float*)d_in[30]; const float* vb1 = (const float*)d_in[31];
  const float* vw2 = (const float*)d_in[32]; const float* vb2 = (const float*)d_in[33];

  float* out = (float*)d_out;
  char* ws = (char*)d_ws;
  u32*  hist3 = (u32*)(ws+OFF_H3);
  u32*  cnt3  = (u32*)(ws+OFF_C3);
  u32*  histS = (u32*)(ws+OFF_HS);
  u32*  cntS  = (u32*)(ws+OFF_CS);
  u32*  pref3 = (u32*)(ws+OFF_P3);
  u32*  keys3 = (u32*)(ws+OFF_K3);
  u32*  lo3   = (u32*)(ws+OFF_L3);
  float* r3   = (float*)(ws+OFF_R3);
  u32*  keysS = (u32*)(ws+OFF_KSC);
  u64*  cand  = (u64*)(ws+OFF_CAND);
  Ctrl* ctrl  = (Ctrl*)(ws+OFF_CTRL);
  int*  idxb  = (int*)(ws+OFF_IDX);
  float* simv = (float*)(ws+OFF_SIM);
  float* sel  = (float*)(ws+OFF_SEL);
  float* hm   = (float*)(ws+OFF_HM);
  float* ht   = (float*)(ws+OFF_HT);
  float* avm  = (float*)(ws+OFF_AVM);
  float* avt  = (float*)(ws+OFF_AVT);
  float* rew  = (float*)(ws+OFF_REW);
  float* vecs = (float*)(ws+OFF_VECS);
  float* lnb  = (float*)(ws+OFF_LNB);
  float* qkvb = (float*)(ws+OFF_QKV);
  float* attn = (float*)(ws+OFF_ATT);
  float* ffh  = (float*)(ws+OFF_FFH);
  float* vhin = (float*)(ws+OFF_VHIN);
  float* vhh  = (float*)(ws+OFF_VHH);
  float* vp   = (float*)(ws+OFF_VP);
  float* part = (float*)(ws+OFF_PART);

  dim3 b256(256);
  int gN = NM/256;

  // ---- single upfront zeroing of all histogram/counter regions ----
  (void)hipMemsetAsync(ws, 0, ZERO_BYTES, stream);

  // ---- scoring ----
  hipLaunchKernelGGL(k_sim2, dim3(NM/4), b256, 0, stream, mv, x, simv);
  hipLaunchKernelGGL(k_keyhist3, dim3(gN), b256, 0, stream, surp, simv, noise, keys3, hist3);
  hipLaunchKernelGGL(k_scan3, dim3(3), dim3(1024), 0, stream, hist3, pref3);
  hipLaunchKernelGGL(k_scatter3, dim3(gN), b256, 0, stream, keys3, pref3, cnt3, lo3);
  hipLaunchKernelGGL(k_rank3, dim3(gN), b256, 0, stream, keys3, pref3, lo3, r3);
  hipLaunchKernelGGL(k_score, dim3(gN), b256, 0, stream, r3, keysS, histS);
  hipLaunchKernelGGL(k_sel1, dim3(1), dim3(1024), 0, stream, histS, ctrl);
  hipLaunchKernelGGL(k_histlo, dim3(gN), b256, 0, stream, keysS, ctrl, cntS);
  hipLaunchKernelGGL(k_sel2, dim3(1), dim3(1024), 0, stream, cntS, ctrl);
  hipLaunchKernelGGL(k_collect, dim3(gN), b256, 0, stream, keysS, ctrl, cand);
  hipLaunchKernelGGL(k_sortsel, dim3(1), dim3(1024), 0, stream, cand, ctrl, idxb);

  // ---- GEMM helper ----
  auto gemm = [&](const float* A, const float* Bw, const float* bias, const float* res,
                  float* C, int M, int N, int K, int S, int act){
    int nbm = (M + 63) / 64, nbn = N / 64;
    int nwg = nbm * nbn * S;
    if(S == 1){
      if(act == 1)
        hipLaunchKernelGGL((gemm_part<1,false,true>), dim3(nwg), b256, 0, stream, A, Bw, bias, res, C, M, N, K, 1, nbm);
      else if(res)
        hipLaunchKernelGGL((gemm_part<0,true,true>),  dim3(nwg), b256, 0, stream, A, Bw, bias, res, C, M, N, K, 1, nbm);
      else
        hipLaunchKernelGGL((gemm_part<0,false,true>), dim3(nwg), b256, 0, stream, A, Bw, bias, res, C, M, N, K, 1, nbm);
    } else {
      hipLaunchKernelGGL((gemm_part<0,false,false>), dim3(nwg), b256, 0, stream, A, Bw, bias, res, part, M, N, K, S, nbm);
      int MN = M * N;
      int g = (MN + 255) / 256;
      if(act == 1)  hipLaunchKernelGGL((k_fin<1,false>), dim3(g), b256, 0, stream, part, bias, res, C, MN, N, S);
      else if(res)  hipLaunchKernelGGL((k_fin<0,true>),  dim3(g), b256, 0, stream, part, bias, res, C, MN, N, S);
      else          hipLaunchKernelGGL((k_fin<0,false>), dim3(g), b256, 0, stream, part, bias, res, C, MN, N, S);
    }
  };

  // ---- gathers + action MLP ----
  hipLaunchKernelGGL(k_gather, dim3(KS), b256, 0, stream, idxb, mv, mnv, mrew, aim, ait,
                     amw1, amb1, atw1, atb1, sel, out + OUT_NEXT, hm, ht, rew, out + OUT_REWO);
  gemm(hm, amw2, amb2, nullptr, avm, KS, HD, HD, 8, 0);
  gemm(ht, atw2, atb2, nullptr, avt, KS, HD, HD, 8, 0);
  hipLaunchKernelGGL(k_assemble, dim3(SQ), b256, 0, stream, start, x, sel, avm, avt, pos, vecs);

  // ---- transformer ----
  for(int l=0;l<NL;++l){
    hipLaunchKernelGGL(k_ln, dim3(SQ), b256, 0, stream, vecs, l1w + (size_t)l*HD, l1b + (size_t)l*HD, lnb);
    gemm(lnb, inW + (size_t)l*3*HD*HD, inB + (size_t)l*3*HD, nullptr, qkvb, SQ, 3*HD, HD, 1, 0);
    hipLaunchKernelGGL(k_attn, dim3(SQ, NH_), b256, 0, stream, qkvb, attn);
    gemm(attn, oW + (size_t)l*HD*HD, oB + (size_t)l*HD, vecs, vecs, SQ, HD, HD, 4, 0);
    hipLaunchKernelGGL(k_ln, dim3(SQ), b256, 0, stream, vecs, l2w + (size_t)l*HD, l2b + (size_t)l*HD, lnb);
    gemm(lnb, f1w + (size_t)l*4*HD*HD, f1b + (size_t)l*4*HD, nullptr, ffh, SQ, 4*HD, HD, 1, 1);
    gemm(ffh, f2w + (size_t)l*HD*4*HD, f2b + (size_t)l*HD, vecs, vecs, SQ, HD, 4*HD, 4, 0);
  }

  // ---- value head + outputs ----
  hipLaunchKernelGGL(k_vhin, dim3(KS+1), b256, 0, stream, vecs, vhin);
  gemm(vhin, vw1, vb1, nullptr, vhh, KS+1, 4*HD, HD, 1, 1);
  hipLaunchKernelGGL(k_vp, dim3(KS+1), b256, 0, stream, vhh, vw2, vb2, vp);
  hipLaunchKernelGGL(k_outvecs, dim3(257*HD/256), b256, 0, stream, vecs, out);
  hipLaunchKernelGGL(k_outsmall, dim3(1), b256, 0, stream, vp, rew, out);
}